// Round 18
// baseline (398.285 us; speedup 1.0000x reference)
//
#include <hip/hip_runtime.h>
#include <math.h>

#define BATCH 2
#define SEQ   2048
#define DIMIN 1024
#define NHEAD 8
#define DHEAD 64
#define INNER 512
#define KNEI  64
#define SCALE 0.125f
#define GBAND 2e-6f     // ambiguity band: ~2x cross-implementation score noise

typedef float v4f __attribute__((ext_vector_type(4)));   // native vec for NT store

// ---------------------------------------------------------------------------
// K1 v6: q = x@Wq, k = x@Wk. 64(m)x128(n) tile, 8x8 microtile, BK=32,
// 128 threads (2 waves), 512 blocks = 2 blocks/CU.
// LDS ratio: 4 b128-reads / 64 FMA (2x better than the 150us 4x4 kernels).
// Chain: single acc, kk ascending 0..1023, fmaf — bit-identical scores.
// ---------------------------------------------------------------------------
__global__ __launch_bounds__(128) void proj_kernel(
    const float* __restrict__ x, const float* __restrict__ Wq,
    const float* __restrict__ Wk, float* __restrict__ qk)
{
  const int which = blockIdx.z;                 // 0 = q, 1 = k
  const float* __restrict__ W = which ? Wk : Wq;
  float* __restrict__ out = qk + (size_t)which * (4096ull * (size_t)INNER);
  const int m0 = blockIdx.y * 64;
  const int n0 = blockIdx.x * 128;
  __shared__ float aT[32][68];    // x tile transposed [k][m]
  __shared__ float bS[32][136];   // W tile [k][n] (K2's proven layout)
  const int t  = threadIdx.x;     // 0..127
  const int ty = t >> 4;          // 0..7   -> m = ty*8
  const int tx = t & 15;          // 0..15  -> n = tx*8
  float acc[8][8] = {};
  for (int k0 = 0; k0 < DIMIN; k0 += 32) {
    { // stage A: 64 m x 32 k; thread: row m=t>>1, k-chunk c=(t&1)*16
      const int m = t >> 1, c = (t & 1) * 16;
      const float* xr = x + (size_t)(m0 + m) * DIMIN + k0 + c;
      #pragma unroll
      for (int s = 0; s < 4; ++s) {
        float4 v = *(const float4*)(xr + s*4);
        aT[c+s*4+0][m] = v.x; aT[c+s*4+1][m] = v.y;
        aT[c+s*4+2][m] = v.z; aT[c+s*4+3][m] = v.w;
      }
    }
    { // stage B: 32 k x 128 n; thread: k-row kk=t>>2, n-chunk (t&3)*32
      const int kk = t >> 2, n = (t & 3) * 32;
      const float* wr = W + (size_t)(k0 + kk) * INNER + n0 + n;
      #pragma unroll
      for (int s = 0; s < 8; ++s)
        *(float4*)&bS[kk][n + s*4] = *(const float4*)(wr + s*4);
    }
    __syncthreads();
    #pragma unroll 4
    for (int kk = 0; kk < 32; ++kk) {   // strictly sequential in global k
      float4 a0 = *(const float4*)&aT[kk][ty*8];
      float4 a1 = *(const float4*)&aT[kk][ty*8+4];
      float4 b0 = *(const float4*)&bS[kk][tx*8];
      float4 b1 = *(const float4*)&bS[kk][tx*8+4];
      float a[8] = {a0.x,a0.y,a0.z,a0.w,a1.x,a1.y,a1.z,a1.w};
      float b[8] = {b0.x,b0.y,b0.z,b0.w,b1.x,b1.y,b1.z,b1.w};
      #pragma unroll
      for (int i = 0; i < 8; ++i)
        #pragma unroll
        for (int j = 0; j < 8; ++j)
          acc[i][j] = fmaf(a[i], b[j], acc[i][j]);
    }
    __syncthreads();
  }
  #pragma unroll
  for (int i = 0; i < 8; ++i) {
    float* orow = out + (size_t)(m0 + ty*8 + i) * INNER + n0 + tx*8;
    *(float4*)(orow)     = make_float4(acc[i][0], acc[i][1], acc[i][2], acc[i][3]);
    *(float4*)(orow + 4) = make_float4(acc[i][4], acc[i][5], acc[i][6], acc[i][7]);
  }
}

// ---------------------------------------------------------------------------
// K2: scores = q @ k^T * SCALE per (b,h).  128x128 tile, 8x8 microtile,
// one-shot LDS stage (K=64).  kk ascending 0..63, single acc — bit-identical.
// (write-BW bound at ~3.5 TB/s; structurally done)
// ---------------------------------------------------------------------------
__global__ __launch_bounds__(256) void score_kernel(
    const float* __restrict__ qk, float* __restrict__ out)
{
  const int bh = blockIdx.z;            // b*8+h
  const int b  = bh >> 3, h = bh & 7;
  const int m0 = blockIdx.y * 128;      // q rows
  const int n0 = blockIdx.x * 128;      // keys
  const float* __restrict__ q = qk;
  const float* __restrict__ k = qk + 4096ull * (size_t)INNER;
  __shared__ float qT[64][136];         // [d][m]
  __shared__ float kT[64][136];         // [d][key]
  const int t = threadIdx.x;
  {
    #pragma unroll
    for (int p = 0; p < 2; ++p) {
      const int r  = p*64 + (t >> 2);       // tile row 0..127
      const int d0 = (t & 3) * 16;          // within-row d base
      const float* qrow = q + (size_t)(b*SEQ + m0 + r) * INNER + h*DHEAD + d0;
      const float* krow = k + (size_t)(b*SEQ + n0 + r) * INNER + h*DHEAD + d0;
      #pragma unroll
      for (int s = 0; s < 4; ++s) {
        float4 qv = *(const float4*)(qrow + s*4);
        float4 kv = *(const float4*)(krow + s*4);
        qT[d0+s*4+0][r] = qv.x; qT[d0+s*4+1][r] = qv.y;
        qT[d0+s*4+2][r] = qv.z; qT[d0+s*4+3][r] = qv.w;
        kT[d0+s*4+0][r] = kv.x; kT[d0+s*4+1][r] = kv.y;
        kT[d0+s*4+2][r] = kv.z; kT[d0+s*4+3][r] = kv.w;
      }
    }
  }
  __syncthreads();
  const int ty = t >> 4, tx = t & 15;
  float acc[8][8] = {};
  #pragma unroll 2
  for (int kk = 0; kk < 64; ++kk) {
    float4 a0 = *(const float4*)&qT[kk][ty*8];
    float4 a1 = *(const float4*)&qT[kk][ty*8+4];
    float4 b0 = *(const float4*)&kT[kk][tx*8];
    float4 b1 = *(const float4*)&kT[kk][tx*8+4];
    float a[8] = {a0.x,a0.y,a0.z,a0.w,a1.x,a1.y,a1.z,a1.w};
    float bb[8]= {b0.x,b0.y,b0.z,b0.w,b1.x,b1.y,b1.z,b1.w};
    #pragma unroll
    for (int i = 0; i < 8; ++i)
      #pragma unroll
      for (int j = 0; j < 8; ++j)
        acc[i][j] = fmaf(a[i], bb[j], acc[i][j]);
  }
  #pragma unroll
  for (int i = 0; i < 8; ++i) {
    float* orow = out + ((size_t)bh * SEQ + m0 + ty*8 + i) * SEQ + n0 + tx*8;
    *(float4*)(orow)     = make_float4(acc[i][0]*SCALE, acc[i][1]*SCALE,
                                       acc[i][2]*SCALE, acc[i][3]*SCALE);
    *(float4*)(orow + 4) = make_float4(acc[i][4]*SCALE, acc[i][5]*SCALE,
                                       acc[i][6]*SCALE, acc[i][7]*SCALE);
  }
}

// ---------------------------------------------------------------------------
// K3 (r15's proven 128us version): per-row top-64 + hedged softmax, in place.
// 1 row/wave, reversed row order (LLC reuse) + NT final stores.
// ---------------------------------------------------------------------------
__device__ __forceinline__ unsigned f2key(float f) {
  unsigned u = __float_as_uint(f);
  return (u & 0x80000000u) ? ~u : (u | 0x80000000u);
}
__device__ __forceinline__ float key2f(unsigned kk) {
  unsigned u = (kk & 0x80000000u) ? (kk & 0x7FFFFFFFu) : ~kk;
  return __uint_as_float(u);
}

__global__ __launch_bounds__(256) void topk_softmax_hedge(float* __restrict__ out)
{
  const int wave = threadIdx.x >> 6;
  const int lane = threadIdx.x & 63;
  const size_t row = (size_t)(gridDim.x - 1 - blockIdx.x) * 4 + wave;  // reversed
  float* __restrict__ p = out + row * (size_t)SEQ;

  float s[32];
  #pragma unroll
  for (int i = 0; i < 8; ++i) {
    float4 v = *(const float4*)(p + (size_t)(lane + 64*i) * 4);
    s[i*4+0] = v.x; s[i*4+1] = v.y; s[i*4+2] = v.z; s[i*4+3] = v.w;
  }

  float mx = s[0], mn = s[0];
  #pragma unroll
  for (int i = 1; i < 32; ++i) { mx = fmaxf(mx, s[i]); mn = fminf(mn, s[i]); }
  #pragma unroll
  for (int o = 32; o; o >>= 1) {
    mx = fmaxf(mx, __shfl_xor(mx, o));
    mn = fminf(mn, __shfl_xor(mn, o));
  }

  // bisection with ballot counting; early exit at count==64.
  unsigned lo = f2key(mn);
  unsigned hi = f2key(mx) + 1u;
  while (lo + 1u < hi) {
    const unsigned mid = lo + ((hi - lo) >> 1);
    const float tf = key2f(mid);
    int c = 0;
    #pragma unroll
    for (int i = 0; i < 32; ++i)
      c += __popcll(__ballot(s[i] >= tf));          // wave-uniform
    if (c >= KNEI) { lo = mid; if (c == KNEI) break; }
    else hi = mid;
  }
  const float thr0 = key2f(lo);   // kept set {s >= thr0} == exact top-64 set

  // exact s64 = min over kept set
  float mk = 3.4e38f;
  #pragma unroll
  for (int i = 0; i < 32; ++i) mk = (s[i] >= thr0) ? fminf(mk, s[i]) : mk;
  #pragma unroll
  for (int o = 32; o; o >>= 1) mk = fminf(mk, __shfl_xor(mk, o));
  const float s64 = mk;

  // ambiguity classification (wave-uniform via ballot)
  int n_hi = 0, n_band = 0;
  #pragma unroll
  for (int i = 0; i < 32; ++i) {
    n_hi   += __popcll(__ballot(s[i] > s64 + GBAND));
    n_band += __popcll(__ballot(fabsf(s[i] - s64) <= GBAND));
  }
  const int r = KNEI - n_hi;
  const bool amb = (n_band != r);
  float fb = (float)r / (float)max(n_band, 1);
  fb = fminf(fmaxf(fb, 0.f), 1.f);

  float z = 0.f;
  #pragma unroll
  for (int i = 0; i < 32; ++i) {
    float f;
    if (amb) {
      f = (s[i] > s64 + GBAND) ? 1.f
        : ((fabsf(s[i] - s64) <= GBAND) ? fb : 0.f);
    } else {
      f = (s[i] >= s64) ? 1.f : 0.f;
    }
    float ex = f * __expf(s[i] - mx);
    s[i] = ex; z += ex;
  }
  #pragma unroll
  for (int o = 32; o; o >>= 1) z += __shfl_xor(z, o);
  const float rz = 1.0f / z;

  #pragma unroll
  for (int i = 0; i < 8; ++i) {
    v4f v = { s[i*4+0]*rz, s[i*4+1]*rz, s[i*4+2]*rz, s[i*4+3]*rz };
    __builtin_nontemporal_store(v, (v4f*)(p + (size_t)(lane + 64*i) * 4));
  }
}

// ---------------------------------------------------------------------------
extern "C" void kernel_launch(void* const* d_in, const int* in_sizes, int n_in,
                              void* d_out, int out_size, void* d_ws, size_t ws_size,
                              hipStream_t stream) {
  const float* x  = (const float*)d_in[0];
  const float* Wq = (const float*)d_in[1];
  const float* Wk = (const float*)d_in[2];
  float* out = (float*)d_out;
  float* ws  = (float*)d_ws;   // 2 * 4096*512 * 4B = 16 MB

  proj_kernel<<<dim3(INNER/128, (BATCH*SEQ)/64, 2), 128, 0, stream>>>(x, Wq, Wk, ws);
  score_kernel<<<dim3(SEQ/128, SEQ/128, BATCH*NHEAD), 256, 0, stream>>>(ws, out);
  topk_softmax_hedge<<<dim3((BATCH*NHEAD*SEQ)/4), 256, 0, stream>>>(out);
}

// Round 19
// 397.000 us; speedup vs baseline: 1.0032x; 1.0032x over previous
//
#include <hip/hip_runtime.h>
#include <math.h>

#define BATCH 2
#define SEQ   2048
#define DIMIN 1024
#define NHEAD 8
#define DHEAD 64
#define INNER 512
#define KNEI  64
#define SCALE 0.125f
#define GBAND 2e-6f     // ambiguity band: ~2x cross-implementation score noise

typedef float v4f __attribute__((ext_vector_type(4)));   // native vec for NT store

// column permutation: spreads 32B-strided b128 lane addresses across all
// banks (4-way -> 2-way=free). 16B alignment preserved (adds multiples of 4).
__device__ __forceinline__ int perm(int n) { return n + ((n >> 5) << 2); }

// ---------------------------------------------------------------------------
// K1 v7: q = x@Wq, k = x@Wk. 64(m)x128(n) tile, 8x8 microtile, BK=32,
// 128 threads, 512 blocks. B and A tiles stored with perm() columns to kill
// the 4-way bank conflict that sank r18 (15.7M conflicts).
// Chain: single acc, kk ascending 0..1023, fmaf — bit-identical scores.
// ---------------------------------------------------------------------------
__global__ __launch_bounds__(128) void proj_kernel(
    const float* __restrict__ x, const float* __restrict__ Wq,
    const float* __restrict__ Wk, float* __restrict__ qk)
{
  const int which = blockIdx.z;                 // 0 = q, 1 = k
  const float* __restrict__ W = which ? Wk : Wq;
  float* __restrict__ out = qk + (size_t)which * (4096ull * (size_t)INNER);
  const int m0 = blockIdx.y * 64;
  const int n0 = blockIdx.x * 128;
  __shared__ float aT[32][68];     // x tile transposed [k][m] (2-way free)
  __shared__ float bS[32][144];    // W tile [k][perm(n)]
  const int t  = threadIdx.x;      // 0..127
  const int ty = t >> 4;           // 0..7   -> m = ty*8
  const int tx = t & 15;           // 0..15  -> n = tx*8
  const int pb0 = perm(tx*8);      // = tx*8 + (tx>>2)*4 ; +4 stays in block
  float acc[8][8] = {};
  for (int k0 = 0; k0 < DIMIN; k0 += 32) {
    { // stage A: 64 m x 32 k; thread: row m=t>>1, k-chunk c=(t&1)*16
      const int m = t >> 1, c = (t & 1) * 16;
      const float* xr = x + (size_t)(m0 + m) * DIMIN + k0 + c;
      #pragma unroll
      for (int s = 0; s < 4; ++s) {
        float4 v = *(const float4*)(xr + s*4);
        aT[c+s*4+0][m] = v.x; aT[c+s*4+1][m] = v.y;
        aT[c+s*4+2][m] = v.z; aT[c+s*4+3][m] = v.w;
      }
    }
    { // stage B: 32 k x 128 n; thread: k-row kk=t>>2, n-chunk (t&3)*32
      const int kk = t >> 2, n = (t & 3) * 32;
      const float* wr = W + (size_t)(k0 + kk) * INNER + n0 + n;
      #pragma unroll
      for (int s = 0; s < 8; ++s)
        *(float4*)&bS[kk][perm(n + s*4)] = *(const float4*)(wr + s*4);
    }
    __syncthreads();
    #pragma unroll 4
    for (int kk = 0; kk < 32; ++kk) {   // strictly sequential in global k
      float4 a0 = *(const float4*)&aT[kk][ty*8];
      float4 a1 = *(const float4*)&aT[kk][ty*8+4];
      float4 b0 = *(const float4*)&bS[kk][pb0];
      float4 b1 = *(const float4*)&bS[kk][pb0+4];
      float a[8] = {a0.x,a0.y,a0.z,a0.w,a1.x,a1.y,a1.z,a1.w};
      float b[8] = {b0.x,b0.y,b0.z,b0.w,b1.x,b1.y,b1.z,b1.w};
      #pragma unroll
      for (int i = 0; i < 8; ++i)
        #pragma unroll
        for (int j = 0; j < 8; ++j)
          acc[i][j] = fmaf(a[i], b[j], acc[i][j]);
    }
    __syncthreads();
  }
  #pragma unroll
  for (int i = 0; i < 8; ++i) {
    float* orow = out + (size_t)(m0 + ty*8 + i) * INNER + n0 + tx*8;
    *(float4*)(orow)     = make_float4(acc[i][0], acc[i][1], acc[i][2], acc[i][3]);
    *(float4*)(orow + 4) = make_float4(acc[i][4], acc[i][5], acc[i][6], acc[i][7]);
  }
}

// ---------------------------------------------------------------------------
// K2: scores = q @ k^T * SCALE per (b,h).  128x128 tile, 8x8 microtile,
// one-shot LDS stage (K=64).  kk ascending 0..63, single acc — bit-identical.
// ---------------------------------------------------------------------------
__global__ __launch_bounds__(256) void score_kernel(
    const float* __restrict__ qk, float* __restrict__ out)
{
  const int bh = blockIdx.z;            // b*8+h
  const int b  = bh >> 3, h = bh & 7;
  const int m0 = blockIdx.y * 128;      // q rows
  const int n0 = blockIdx.x * 128;      // keys
  const float* __restrict__ q = qk;
  const float* __restrict__ k = qk + 4096ull * (size_t)INNER;
  __shared__ float qT[64][136];         // [d][m]
  __shared__ float kT[64][136];         // [d][key]
  const int t = threadIdx.x;
  {
    #pragma unroll
    for (int p = 0; p < 2; ++p) {
      const int r  = p*64 + (t >> 2);       // tile row 0..127
      const int d0 = (t & 3) * 16;          // within-row d base
      const float* qrow = q + (size_t)(b*SEQ + m0 + r) * INNER + h*DHEAD + d0;
      const float* krow = k + (size_t)(b*SEQ + n0 + r) * INNER + h*DHEAD + d0;
      #pragma unroll
      for (int s = 0; s < 4; ++s) {
        float4 qv = *(const float4*)(qrow + s*4);
        float4 kv = *(const float4*)(krow + s*4);
        qT[d0+s*4+0][r] = qv.x; qT[d0+s*4+1][r] = qv.y;
        qT[d0+s*4+2][r] = qv.z; qT[d0+s*4+3][r] = qv.w;
        kT[d0+s*4+0][r] = kv.x; kT[d0+s*4+1][r] = kv.y;
        kT[d0+s*4+2][r] = kv.z; kT[d0+s*4+3][r] = kv.w;
      }
    }
  }
  __syncthreads();
  const int ty = t >> 4, tx = t & 15;
  float acc[8][8] = {};
  #pragma unroll 2
  for (int kk = 0; kk < 64; ++kk) {
    float4 a0 = *(const float4*)&qT[kk][ty*8];
    float4 a1 = *(const float4*)&qT[kk][ty*8+4];
    float4 b0 = *(const float4*)&kT[kk][tx*8];
    float4 b1 = *(const float4*)&kT[kk][tx*8+4];
    float a[8] = {a0.x,a0.y,a0.z,a0.w,a1.x,a1.y,a1.z,a1.w};
    float bb[8]= {b0.x,b0.y,b0.z,b0.w,b1.x,b1.y,b1.z,b1.w};
    #pragma unroll
    for (int i = 0; i < 8; ++i)
      #pragma unroll
      for (int j = 0; j < 8; ++j)
        acc[i][j] = fmaf(a[i], bb[j], acc[i][j]);
  }
  #pragma unroll
  for (int i = 0; i < 8; ++i) {
    float* orow = out + ((size_t)bh * SEQ + m0 + ty*8 + i) * SEQ + n0 + tx*8;
    *(float4*)(orow)     = make_float4(acc[i][0]*SCALE, acc[i][1]*SCALE,
                                       acc[i][2]*SCALE, acc[i][3]*SCALE);
    *(float4*)(orow + 4) = make_float4(acc[i][4]*SCALE, acc[i][5]*SCALE,
                                       acc[i][6]*SCALE, acc[i][7]*SCALE);
  }
}

// ---------------------------------------------------------------------------
// K3 (r15's proven version): per-row top-64 + hedged softmax, in place.
// 1 row/wave, reversed row order (LLC reuse) + NT final stores.
// ---------------------------------------------------------------------------
__device__ __forceinline__ unsigned f2key(float f) {
  unsigned u = __float_as_uint(f);
  return (u & 0x80000000u) ? ~u : (u | 0x80000000u);
}
__device__ __forceinline__ float key2f(unsigned kk) {
  unsigned u = (kk & 0x80000000u) ? (kk & 0x7FFFFFFFu) : ~kk;
  return __uint_as_float(u);
}

__global__ __launch_bounds__(256) void topk_softmax_hedge(float* __restrict__ out)
{
  const int wave = threadIdx.x >> 6;
  const int lane = threadIdx.x & 63;
  const size_t row = (size_t)(gridDim.x - 1 - blockIdx.x) * 4 + wave;  // reversed
  float* __restrict__ p = out + row * (size_t)SEQ;

  float s[32];
  #pragma unroll
  for (int i = 0; i < 8; ++i) {
    float4 v = *(const float4*)(p + (size_t)(lane + 64*i) * 4);
    s[i*4+0] = v.x; s[i*4+1] = v.y; s[i*4+2] = v.z; s[i*4+3] = v.w;
  }

  float mx = s[0], mn = s[0];
  #pragma unroll
  for (int i = 1; i < 32; ++i) { mx = fmaxf(mx, s[i]); mn = fminf(mn, s[i]); }
  #pragma unroll
  for (int o = 32; o; o >>= 1) {
    mx = fmaxf(mx, __shfl_xor(mx, o));
    mn = fminf(mn, __shfl_xor(mn, o));
  }

  // bisection with ballot counting; early exit at count==64.
  unsigned lo = f2key(mn);
  unsigned hi = f2key(mx) + 1u;
  while (lo + 1u < hi) {
    const unsigned mid = lo + ((hi - lo) >> 1);
    const float tf = key2f(mid);
    int c = 0;
    #pragma unroll
    for (int i = 0; i < 32; ++i)
      c += __popcll(__ballot(s[i] >= tf));          // wave-uniform
    if (c >= KNEI) { lo = mid; if (c == KNEI) break; }
    else hi = mid;
  }
  const float thr0 = key2f(lo);   // kept set {s >= thr0} == exact top-64 set

  // exact s64 = min over kept set
  float mk = 3.4e38f;
  #pragma unroll
  for (int i = 0; i < 32; ++i) mk = (s[i] >= thr0) ? fminf(mk, s[i]) : mk;
  #pragma unroll
  for (int o = 32; o; o >>= 1) mk = fminf(mk, __shfl_xor(mk, o));
  const float s64 = mk;

  // ambiguity classification (wave-uniform via ballot)
  int n_hi = 0, n_band = 0;
  #pragma unroll
  for (int i = 0; i < 32; ++i) {
    n_hi   += __popcll(__ballot(s[i] > s64 + GBAND));
    n_band += __popcll(__ballot(fabsf(s[i] - s64) <= GBAND));
  }
  const int r = KNEI - n_hi;
  const bool amb = (n_band != r);
  float fb = (float)r / (float)max(n_band, 1);
  fb = fminf(fmaxf(fb, 0.f), 1.f);

  float z = 0.f;
  #pragma unroll
  for (int i = 0; i < 32; ++i) {
    float f;
    if (amb) {
      f = (s[i] > s64 + GBAND) ? 1.f
        : ((fabsf(s[i] - s64) <= GBAND) ? fb : 0.f);
    } else {
      f = (s[i] >= s64) ? 1.f : 0.f;
    }
    float ex = f * __expf(s[i] - mx);
    s[i] = ex; z += ex;
  }
  #pragma unroll
  for (int o = 32; o; o >>= 1) z += __shfl_xor(z, o);
  const float rz = 1.0f / z;

  #pragma unroll
  for (int i = 0; i < 8; ++i) {
    v4f v = { s[i*4+0]*rz, s[i*4+1]*rz, s[i*4+2]*rz, s[i*4+3]*rz };
    __builtin_nontemporal_store(v, (v4f*)(p + (size_t)(lane + 64*i) * 4));
  }
}

// ---------------------------------------------------------------------------
extern "C" void kernel_launch(void* const* d_in, const int* in_sizes, int n_in,
                              void* d_out, int out_size, void* d_ws, size_t ws_size,
                              hipStream_t stream) {
  const float* x  = (const float*)d_in[0];
  const float* Wq = (const float*)d_in[1];
  const float* Wk = (const float*)d_in[2];
  float* out = (float*)d_out;
  float* ws  = (float*)d_ws;   // 2 * 4096*512 * 4B = 16 MB

  proj_kernel<<<dim3(INNER/128, (BATCH*SEQ)/64, 2), 128, 0, stream>>>(x, Wq, Wk, ws);
  score_kernel<<<dim3(SEQ/128, SEQ/128, BATCH*NHEAD), 256, 0, stream>>>(ws, out);
  topk_softmax_hedge<<<dim3((BATCH*NHEAD*SEQ)/4), 256, 0, stream>>>(out);
}

// Round 20
// 390.643 us; speedup vs baseline: 1.0196x; 1.0163x over previous
//
#include <hip/hip_runtime.h>
#include <math.h>

#define BATCH 2
#define SEQ   2048
#define DIMIN 1024
#define NHEAD 8
#define DHEAD 64
#define INNER 512
#define KNEI  64
#define SCALE 0.125f
#define GBAND 2e-6f     // ambiguity band: ~2x cross-implementation score noise

typedef float v4f __attribute__((ext_vector_type(4)));   // native vec for NT store

// ---------------------------------------------------------------------------
// K1 v8: q = x@Wq, k = x@Wk. 64(m)x32(n) tile, 4x2 microtile, BK=16,
// 256 threads, 2048 blocks = 8 blocks/CU = FULL 32 waves/CU occupancy.
// Theory: all prior variants were <=4 waves/SIMD (latency-bound at ~150us,
// VALUBusy<46%); this trades LDS-instr ratio for 2x wave count.
// Chain: single acc, kk ascending 0..1023, fmaf — bit-identical scores.
// ---------------------------------------------------------------------------
__global__ __launch_bounds__(256) void proj_kernel(
    const float* __restrict__ x, const float* __restrict__ Wq,
    const float* __restrict__ Wk, float* __restrict__ qk)
{
  const int which = blockIdx.z;                 // 0 = q, 1 = k
  const float* __restrict__ W = which ? Wk : Wq;
  float* __restrict__ out = qk + (size_t)which * (4096ull * (size_t)INNER);
  const int m0 = blockIdx.y * 64;
  const int n0 = blockIdx.x * 32;
  __shared__ float aT[16][68];   // x tile transposed [k][m]
  __shared__ float bS[16][36];   // W tile [k][n]
  const int t  = threadIdx.x;
  const int ty = t >> 4, tx = t & 15;   // micro: m=ty*4..+3, n=tx*2..+1
  float acc[4][2] = {};
  for (int k0 = 0; k0 < DIMIN; k0 += 16) {
    { // stage A: 64 m x 16 k, one float4/thread (same as r15)
      const int m = t >> 2, c4 = t & 3;
      float4 av = *(const float4*)(x + (size_t)(m0 + m) * DIMIN + k0 + c4 * 4);
      aT[c4*4+0][m] = av.x; aT[c4*4+1][m] = av.y;
      aT[c4*4+2][m] = av.z; aT[c4*4+3][m] = av.w;
    }
    { // stage B: 16 k x 32 n, one float2/thread, coalesced
      const int kk = t >> 4, n = (t & 15) * 2;
      *(float2*)&bS[kk][n] = *(const float2*)(W + (size_t)(k0 + kk) * INNER + n0 + n);
    }
    __syncthreads();
    #pragma unroll 4
    for (int kk = 0; kk < 16; ++kk) {   // strictly sequential in global k
      float4 a4 = *(const float4*)&aT[kk][ty*4];       // broadcast across tx
      float2 b2 = *(const float2*)&bS[kk][tx*2];       // 2-way max (free)
      float a[4] = {a4.x, a4.y, a4.z, a4.w};
      float b[2] = {b2.x, b2.y};
      #pragma unroll
      for (int i = 0; i < 4; ++i)
        #pragma unroll
        for (int j = 0; j < 2; ++j)
          acc[i][j] = fmaf(a[i], b[j], acc[i][j]);
    }
    __syncthreads();
  }
  #pragma unroll
  for (int i = 0; i < 4; ++i) {
    float2 v = make_float2(acc[i][0], acc[i][1]);
    *(float2*)(out + (size_t)(m0 + ty*4 + i) * INNER + n0 + tx*2) = v;
  }
}

// ---------------------------------------------------------------------------
// K2: scores = q @ k^T * SCALE per (b,h).  128x128 tile, 8x8 microtile,
// one-shot LDS stage (K=64).  kk ascending 0..63, single acc — bit-identical.
// ---------------------------------------------------------------------------
__global__ __launch_bounds__(256) void score_kernel(
    const float* __restrict__ qk, float* __restrict__ out)
{
  const int bh = blockIdx.z;            // b*8+h
  const int b  = bh >> 3, h = bh & 7;
  const int m0 = blockIdx.y * 128;      // q rows
  const int n0 = blockIdx.x * 128;      // keys
  const float* __restrict__ q = qk;
  const float* __restrict__ k = qk + 4096ull * (size_t)INNER;
  __shared__ float qT[64][136];         // [d][m]
  __shared__ float kT[64][136];         // [d][key]
  const int t = threadIdx.x;
  {
    #pragma unroll
    for (int p = 0; p < 2; ++p) {
      const int r  = p*64 + (t >> 2);       // tile row 0..127
      const int d0 = (t & 3) * 16;          // within-row d base
      const float* qrow = q + (size_t)(b*SEQ + m0 + r) * INNER + h*DHEAD + d0;
      const float* krow = k + (size_t)(b*SEQ + n0 + r) * INNER + h*DHEAD + d0;
      #pragma unroll
      for (int s = 0; s < 4; ++s) {
        float4 qv = *(const float4*)(qrow + s*4);
        float4 kv = *(const float4*)(krow + s*4);
        qT[d0+s*4+0][r] = qv.x; qT[d0+s*4+1][r] = qv.y;
        qT[d0+s*4+2][r] = qv.z; qT[d0+s*4+3][r] = qv.w;
        kT[d0+s*4+0][r] = kv.x; kT[d0+s*4+1][r] = kv.y;
        kT[d0+s*4+2][r] = kv.z; kT[d0+s*4+3][r] = kv.w;
      }
    }
  }
  __syncthreads();
  const int ty = t >> 4, tx = t & 15;
  float acc[8][8] = {};
  #pragma unroll 2
  for (int kk = 0; kk < 64; ++kk) {
    float4 a0 = *(const float4*)&qT[kk][ty*8];
    float4 a1 = *(const float4*)&qT[kk][ty*8+4];
    float4 b0 = *(const float4*)&kT[kk][tx*8];
    float4 b1 = *(const float4*)&kT[kk][tx*8+4];
    float a[8] = {a0.x,a0.y,a0.z,a0.w,a1.x,a1.y,a1.z,a1.w};
    float bb[8]= {b0.x,b0.y,b0.z,b0.w,b1.x,b1.y,b1.z,b1.w};
    #pragma unroll
    for (int i = 0; i < 8; ++i)
      #pragma unroll
      for (int j = 0; j < 8; ++j)
        acc[i][j] = fmaf(a[i], bb[j], acc[i][j]);
  }
  #pragma unroll
  for (int i = 0; i < 8; ++i) {
    float* orow = out + ((size_t)bh * SEQ + m0 + ty*8 + i) * SEQ + n0 + tx*8;
    *(float4*)(orow)     = make_float4(acc[i][0]*SCALE, acc[i][1]*SCALE,
                                       acc[i][2]*SCALE, acc[i][3]*SCALE);
    *(float4*)(orow + 4) = make_float4(acc[i][4]*SCALE, acc[i][5]*SCALE,
                                       acc[i][6]*SCALE, acc[i][7]*SCALE);
  }
}

// ---------------------------------------------------------------------------
// K3 (r15's proven version): per-row top-64 + hedged softmax, in place.
// 1 row/wave, reversed row order (LLC reuse) + NT final stores.
// ---------------------------------------------------------------------------
__device__ __forceinline__ unsigned f2key(float f) {
  unsigned u = __float_as_uint(f);
  return (u & 0x80000000u) ? ~u : (u | 0x80000000u);
}
__device__ __forceinline__ float key2f(unsigned kk) {
  unsigned u = (kk & 0x80000000u) ? (kk & 0x7FFFFFFFu) : ~kk;
  return __uint_as_float(u);
}

__global__ __launch_bounds__(256) void topk_softmax_hedge(float* __restrict__ out)
{
  const int wave = threadIdx.x >> 6;
  const int lane = threadIdx.x & 63;
  const size_t row = (size_t)(gridDim.x - 1 - blockIdx.x) * 4 + wave;  // reversed
  float* __restrict__ p = out + row * (size_t)SEQ;

  float s[32];
  #pragma unroll
  for (int i = 0; i < 8; ++i) {
    float4 v = *(const float4*)(p + (size_t)(lane + 64*i) * 4);
    s[i*4+0] = v.x; s[i*4+1] = v.y; s[i*4+2] = v.z; s[i*4+3] = v.w;
  }

  float mx = s[0], mn = s[0];
  #pragma unroll
  for (int i = 1; i < 32; ++i) { mx = fmaxf(mx, s[i]); mn = fminf(mn, s[i]); }
  #pragma unroll
  for (int o = 32; o; o >>= 1) {
    mx = fmaxf(mx, __shfl_xor(mx, o));
    mn = fminf(mn, __shfl_xor(mn, o));
  }

  // bisection with ballot counting; early exit at count==64.
  unsigned lo = f2key(mn);
  unsigned hi = f2key(mx) + 1u;
  while (lo + 1u < hi) {
    const unsigned mid = lo + ((hi - lo) >> 1);
    const float tf = key2f(mid);
    int c = 0;
    #pragma unroll
    for (int i = 0; i < 32; ++i)
      c += __popcll(__ballot(s[i] >= tf));          // wave-uniform
    if (c >= KNEI) { lo = mid; if (c == KNEI) break; }
    else hi = mid;
  }
  const float thr0 = key2f(lo);   // kept set {s >= thr0} == exact top-64 set

  // exact s64 = min over kept set
  float mk = 3.4e38f;
  #pragma unroll
  for (int i = 0; i < 32; ++i) mk = (s[i] >= thr0) ? fminf(mk, s[i]) : mk;
  #pragma unroll
  for (int o = 32; o; o >>= 1) mk = fminf(mk, __shfl_xor(mk, o));
  const float s64 = mk;

  // ambiguity classification (wave-uniform via ballot)
  int n_hi = 0, n_band = 0;
  #pragma unroll
  for (int i = 0; i < 32; ++i) {
    n_hi   += __popcll(__ballot(s[i] > s64 + GBAND));
    n_band += __popcll(__ballot(fabsf(s[i] - s64) <= GBAND));
  }
  const int r = KNEI - n_hi;
  const bool amb = (n_band != r);
  float fb = (float)r / (float)max(n_band, 1);
  fb = fminf(fmaxf(fb, 0.f), 1.f);

  float z = 0.f;
  #pragma unroll
  for (int i = 0; i < 32; ++i) {
    float f;
    if (amb) {
      f = (s[i] > s64 + GBAND) ? 1.f
        : ((fabsf(s[i] - s64) <= GBAND) ? fb : 0.f);
    } else {
      f = (s[i] >= s64) ? 1.f : 0.f;
    }
    float ex = f * __expf(s[i] - mx);
    s[i] = ex; z += ex;
  }
  #pragma unroll
  for (int o = 32; o; o >>= 1) z += __shfl_xor(z, o);
  const float rz = 1.0f / z;

  #pragma unroll
  for (int i = 0; i < 8; ++i) {
    v4f v = { s[i*4+0]*rz, s[i*4+1]*rz, s[i*4+2]*rz, s[i*4+3]*rz };
    __builtin_nontemporal_store(v, (v4f*)(p + (size_t)(lane + 64*i) * 4));
  }
}

// ---------------------------------------------------------------------------
extern "C" void kernel_launch(void* const* d_in, const int* in_sizes, int n_in,
                              void* d_out, int out_size, void* d_ws, size_t ws_size,
                              hipStream_t stream) {
  const float* x  = (const float*)d_in[0];
  const float* Wq = (const float*)d_in[1];
  const float* Wk = (const float*)d_in[2];
  float* out = (float*)d_out;
  float* ws  = (float*)d_ws;   // 2 * 4096*512 * 4B = 16 MB

  proj_kernel<<<dim3(INNER/32, (BATCH*SEQ)/64, 2), 256, 0, stream>>>(x, Wq, Wk, ws);
  score_kernel<<<dim3(SEQ/128, SEQ/128, BATCH*NHEAD), 256, 0, stream>>>(ws, out);
  topk_softmax_hedge<<<dim3((BATCH*NHEAD*SEQ)/4), 256, 0, stream>>>(out);
}

// Round 21
// 345.377 us; speedup vs baseline: 1.1532x; 1.1311x over previous
//
#include <hip/hip_runtime.h>
#include <math.h>

#define BATCH 2
#define SEQ   2048
#define DIMIN 1024
#define NHEAD 8
#define DHEAD 64
#define INNER 512
#define KNEI  64
#define SCALE 0.125f
#define GBAND 2e-6f     // ambiguity band: ~2x cross-implementation score noise

typedef float v4f __attribute__((ext_vector_type(4)));   // native vec for NT store

// ---------------------------------------------------------------------------
// K1 v9: q = x@Wq, k = x@Wk. Exact r15 tile (64x64, 4x4 micro, BK=16) +
// REGISTER-PREFETCH double buffering: next tile's global loads issue before
// the compute phase and retire under the ~2000-cycle FMA block. This removes
// the per-iteration exposed load latency (the measured 2.7x dilation over
// the 55us FMA floor common to ALL prior K1 variants).
// Chain: single acc, kk ascending 0..1023, fmaf — bit-identical scores.
// ---------------------------------------------------------------------------
__global__ __launch_bounds__(256) void proj_kernel(
    const float* __restrict__ x, const float* __restrict__ Wq,
    const float* __restrict__ Wk, float* __restrict__ qk)
{
  const int which = blockIdx.z;                 // 0 = q, 1 = k
  const float* __restrict__ W = which ? Wk : Wq;
  float* __restrict__ out = qk + (size_t)which * (4096ull * (size_t)INNER);
  const int m0 = blockIdx.y * 64;
  const int n0 = blockIdx.x * 64;
  __shared__ float aT[16][68];   // x tile transposed [k][m]
  __shared__ float bS[16][68];   // W tile [k][n]
  const int t  = threadIdx.x;
  const int ty = t >> 4, tx = t & 15;
  // staging thread roles (same as r15)
  const int am = t >> 2, ac4 = t & 3;           // A: row m, k-chunk ac4*4
  const int bk = t >> 6, bn = t & 63;           // B: k-row bk(+4s), col bn
  const float* __restrict__ xrow = x + (size_t)(m0 + am) * DIMIN;
  const float* __restrict__ wcol = W + bn + n0;

  float4 ar;        // prefetched A fragment
  float  br[4];     // prefetched B fragment
  // prologue: load tile k0=0 into regs
  ar = *(const float4*)(xrow + 0 + ac4 * 4);
  #pragma unroll
  for (int s5 = 0; s5 < 4; ++s5)
    br[s5] = wcol[(size_t)(0 + bk + 4*s5) * INNER];

  float acc[4][4] = {};
  for (int k0 = 0; k0 < DIMIN; k0 += 16) {
    __syncthreads();   // prior compute done -> safe to overwrite LDS
    aT[ac4*4+0][am] = ar.x; aT[ac4*4+1][am] = ar.y;
    aT[ac4*4+2][am] = ar.z; aT[ac4*4+3][am] = ar.w;
    #pragma unroll
    for (int s5 = 0; s5 < 4; ++s5)
      bS[bk + 4*s5][bn] = br[s5];
    __syncthreads();
    // issue next tile's loads now; they retire under the FMA block below
    if (k0 + 16 < DIMIN) {
      ar = *(const float4*)(xrow + (k0 + 16) + ac4 * 4);
      #pragma unroll
      for (int s5 = 0; s5 < 4; ++s5)
        br[s5] = wcol[(size_t)(k0 + 16 + bk + 4*s5) * INNER];
    }
    #pragma unroll 4
    for (int kk = 0; kk < 16; ++kk) {   // strictly sequential in global k
      float4 a4 = *(const float4*)&aT[kk][ty*4];
      float4 b4 = *(const float4*)&bS[kk][tx*4];
      float a[4] = {a4.x, a4.y, a4.z, a4.w};
      float b[4] = {b4.x, b4.y, b4.z, b4.w};
      #pragma unroll
      for (int i = 0; i < 4; ++i)
        #pragma unroll
        for (int j = 0; j < 4; ++j)
          acc[i][j] = fmaf(a[i], b[j], acc[i][j]);
    }
  }
  #pragma unroll
  for (int i = 0; i < 4; ++i) {
    float4 v = make_float4(acc[i][0], acc[i][1], acc[i][2], acc[i][3]);
    *(float4*)(out + (size_t)(m0 + ty*4 + i) * INNER + n0 + tx*4) = v;
  }
}

// ---------------------------------------------------------------------------
// K2: scores = q @ k^T * SCALE per (b,h).  128x128 tile, 8x8 microtile,
// one-shot LDS stage (K=64).  kk ascending 0..63, single acc — bit-identical.
// ---------------------------------------------------------------------------
__global__ __launch_bounds__(256) void score_kernel(
    const float* __restrict__ qk, float* __restrict__ out)
{
  const int bh = blockIdx.z;            // b*8+h
  const int b  = bh >> 3, h = bh & 7;
  const int m0 = blockIdx.y * 128;      // q rows
  const int n0 = blockIdx.x * 128;      // keys
  const float* __restrict__ q = qk;
  const float* __restrict__ k = qk + 4096ull * (size_t)INNER;
  __shared__ float qT[64][136];         // [d][m]
  __shared__ float kT[64][136];         // [d][key]
  const int t = threadIdx.x;
  {
    #pragma unroll
    for (int p = 0; p < 2; ++p) {
      const int r  = p*64 + (t >> 2);       // tile row 0..127
      const int d0 = (t & 3) * 16;          // within-row d base
      const float* qrow = q + (size_t)(b*SEQ + m0 + r) * INNER + h*DHEAD + d0;
      const float* krow = k + (size_t)(b*SEQ + n0 + r) * INNER + h*DHEAD + d0;
      #pragma unroll
      for (int s = 0; s < 4; ++s) {
        float4 qv = *(const float4*)(qrow + s*4);
        float4 kv = *(const float4*)(krow + s*4);
        qT[d0+s*4+0][r] = qv.x; qT[d0+s*4+1][r] = qv.y;
        qT[d0+s*4+2][r] = qv.z; qT[d0+s*4+3][r] = qv.w;
        kT[d0+s*4+0][r] = kv.x; kT[d0+s*4+1][r] = kv.y;
        kT[d0+s*4+2][r] = kv.z; kT[d0+s*4+3][r] = kv.w;
      }
    }
  }
  __syncthreads();
  const int ty = t >> 4, tx = t & 15;
  float acc[8][8] = {};
  #pragma unroll 2
  for (int kk = 0; kk < 64; ++kk) {
    float4 a0 = *(const float4*)&qT[kk][ty*8];
    float4 a1 = *(const float4*)&qT[kk][ty*8+4];
    float4 b0 = *(const float4*)&kT[kk][tx*8];
    float4 b1 = *(const float4*)&kT[kk][tx*8+4];
    float a[8] = {a0.x,a0.y,a0.z,a0.w,a1.x,a1.y,a1.z,a1.w};
    float bb[8]= {b0.x,b0.y,b0.z,b0.w,b1.x,b1.y,b1.z,b1.w};
    #pragma unroll
    for (int i = 0; i < 8; ++i)
      #pragma unroll
      for (int j = 0; j < 8; ++j)
        acc[i][j] = fmaf(a[i], bb[j], acc[i][j]);
  }
  #pragma unroll
  for (int i = 0; i < 8; ++i) {
    float* orow = out + ((size_t)bh * SEQ + m0 + ty*8 + i) * SEQ + n0 + tx*8;
    *(float4*)(orow)     = make_float4(acc[i][0]*SCALE, acc[i][1]*SCALE,
                                       acc[i][2]*SCALE, acc[i][3]*SCALE);
    *(float4*)(orow + 4) = make_float4(acc[i][4]*SCALE, acc[i][5]*SCALE,
                                       acc[i][6]*SCALE, acc[i][7]*SCALE);
  }
}

// ---------------------------------------------------------------------------
// K3 (r15's proven version): per-row top-64 + hedged softmax, in place.
// 1 row/wave, reversed row order (LLC reuse) + NT final stores.
// ---------------------------------------------------------------------------
__device__ __forceinline__ unsigned f2key(float f) {
  unsigned u = __float_as_uint(f);
  return (u & 0x80000000u) ? ~u : (u | 0x80000000u);
}
__device__ __forceinline__ float key2f(unsigned kk) {
  unsigned u = (kk & 0x80000000u) ? (kk & 0x7FFFFFFFu) : ~kk;
  return __uint_as_float(u);
}

__global__ __launch_bounds__(256) void topk_softmax_hedge(float* __restrict__ out)
{
  const int wave = threadIdx.x >> 6;
  const int lane = threadIdx.x & 63;
  const size_t row = (size_t)(gridDim.x - 1 - blockIdx.x) * 4 + wave;  // reversed
  float* __restrict__ p = out + row * (size_t)SEQ;

  float s[32];
  #pragma unroll
  for (int i = 0; i < 8; ++i) {
    float4 v = *(const float4*)(p + (size_t)(lane + 64*i) * 4);
    s[i*4+0] = v.x; s[i*4+1] = v.y; s[i*4+2] = v.z; s[i*4+3] = v.w;
  }

  float mx = s[0], mn = s[0];
  #pragma unroll
  for (int i = 1; i < 32; ++i) { mx = fmaxf(mx, s[i]); mn = fminf(mn, s[i]); }
  #pragma unroll
  for (int o = 32; o; o >>= 1) {
    mx = fmaxf(mx, __shfl_xor(mx, o));
    mn = fminf(mn, __shfl_xor(mn, o));
  }

  // bisection with ballot counting; early exit at count==64.
  unsigned lo = f2key(mn);
  unsigned hi = f2key(mx) + 1u;
  while (lo + 1u < hi) {
    const unsigned mid = lo + ((hi - lo) >> 1);
    const float tf = key2f(mid);
    int c = 0;
    #pragma unroll
    for (int i = 0; i < 32; ++i)
      c += __popcll(__ballot(s[i] >= tf));          // wave-uniform
    if (c >= KNEI) { lo = mid; if (c == KNEI) break; }
    else hi = mid;
  }
  const float thr0 = key2f(lo);   // kept set {s >= thr0} == exact top-64 set

  // exact s64 = min over kept set
  float mk = 3.4e38f;
  #pragma unroll
  for (int i = 0; i < 32; ++i) mk = (s[i] >= thr0) ? fminf(mk, s[i]) : mk;
  #pragma unroll
  for (int o = 32; o; o >>= 1) mk = fminf(mk, __shfl_xor(mk, o));
  const float s64 = mk;

  // ambiguity classification (wave-uniform via ballot)
  int n_hi = 0, n_band = 0;
  #pragma unroll
  for (int i = 0; i < 32; ++i) {
    n_hi   += __popcll(__ballot(s[i] > s64 + GBAND));
    n_band += __popcll(__ballot(fabsf(s[i] - s64) <= GBAND));
  }
  const int r = KNEI - n_hi;
  const bool amb = (n_band != r);
  float fb = (float)r / (float)max(n_band, 1);
  fb = fminf(fmaxf(fb, 0.f), 1.f);

  float z = 0.f;
  #pragma unroll
  for (int i = 0; i < 32; ++i) {
    float f;
    if (amb) {
      f = (s[i] > s64 + GBAND) ? 1.f
        : ((fabsf(s[i] - s64) <= GBAND) ? fb : 0.f);
    } else {
      f = (s[i] >= s64) ? 1.f : 0.f;
    }
    float ex = f * __expf(s[i] - mx);
    s[i] = ex; z += ex;
  }
  #pragma unroll
  for (int o = 32; o; o >>= 1) z += __shfl_xor(z, o);
  const float rz = 1.0f / z;

  #pragma unroll
  for (int i = 0; i < 8; ++i) {
    v4f v = { s[i*4+0]*rz, s[i*4+1]*rz, s[i*4+2]*rz, s[i*4+3]*rz };
    __builtin_nontemporal_store(v, (v4f*)(p + (size_t)(lane + 64*i) * 4));
  }
}

// ---------------------------------------------------------------------------
extern "C" void kernel_launch(void* const* d_in, const int* in_sizes, int n_in,
                              void* d_out, int out_size, void* d_ws, size_t ws_size,
                              hipStream_t stream) {
  const float* x  = (const float*)d_in[0];
  const float* Wq = (const float*)d_in[1];
  const float* Wk = (const float*)d_in[2];
  float* out = (float*)d_out;
  float* ws  = (float*)d_ws;   // 2 * 4096*512 * 4B = 16 MB

  proj_kernel<<<dim3(INNER/64, (BATCH*SEQ)/64, 2), 256, 0, stream>>>(x, Wq, Wk, ws);
  score_kernel<<<dim3(SEQ/128, SEQ/128, BATCH*NHEAD), 256, 0, stream>>>(ws, out);
  topk_softmax_hedge<<<dim3((BATCH*NHEAD*SEQ)/4), 256, 0, stream>>>(out);
}